// Round 14
// baseline (304.431 us; speedup 1.0000x reference)
//
#include <hip/hip_runtime.h>

// ChildSumTreeLSTM on a static 4-ary heap tree.
// N=8192, H=256, D=300, K=4, OUT=4. Leaves = 2048..8191. Internal 0..2047 in 7 levels.
// Workspace: gx [8192][1024] f32, Hb [8192][256] f32, Cb [8192][256] f32.
// D (big-level scratch, <=7.3MB) aliases gx rows 2048.. (leaf gx never written).
//
// Structure (11 dispatches):
//   1. gx_leaf_gemm — LPT order (384 fat leaf blocks FIRST: 3 gates +
//        in-register leaf pointwise -> Hb/Cb; then 512 internal 64x64 gx
//        tiles), XCD-grouped for emb L2 locality.          [67.3us, r12/r13]
//   2-7. levels M=683,1024,256: level_gemm (64x64, pipelined) +
//        level_pointwise (proven pair).
//   8-10. levels M=64,16,4: tail_fused (W 256KB/block from L2, 2 syncs).
//   11. root_kernel — single block: 7 GEMVs (thread-per-row, W 1MB from L2)
//        + pointwise + logits/log_softmax (round-9-proven).
// Hard rules (rounds 1-13): NO device-scope fences/atomics (170-200us each).
// No chunked W-LDS fused levels (rounds 4/6). Fused GEMV levels ONLY for
// M<=64 (rounds 9/12: scattered W-reads lose to coalesced pairs at big M).
// Dispatch-DAG minimum is 11 under these rules; gaps ~14us each dominate.

#define N_NODES 8192
#define HDIM 256
#define DDIM 300
#define GXC 1024
#define LEAF_FIRST 2048
#define WH_STRIDE 65536   // 256*256
#define XI(k) ((k) + (((k) >> 6) << 2))   // padded X index (bank spread)

__device__ __forceinline__ float sigf(float x) { return 1.0f / (1.0f + __expf(-x)); }

// ---------- Kernel 1: gx internal rows + fused leaf h/c (LPT order) ---------
__global__ __launch_bounds__(256) void gx_leaf_gemm(
    const int* __restrict__ xs, const float* __restrict__ emb,
    const float* __restrict__ Wx, const float* __restrict__ bx,
    const float* __restrict__ bh, float* __restrict__ gx,
    float* __restrict__ Hb, float* __restrict__ Cb)
{
    __shared__ __align__(16) float As[16][68];
    __shared__ __align__(16) float Bs[3][16][68];
    const int lid  = blockIdx.x;
    const int tid  = threadIdx.x;
    const int sr   = tid >> 2;
    const int sk   = (tid & 3) << 2;
    const int trow = (tid >> 4) << 2;
    const int tcol = (tid & 15) << 2;

    if (lid >= 384) {
        // ---------------- internal 64x64 tile (round-5-proven) --------------
        const int l = lid - 384;
        const int xcd = l & 7, idx = l >> 3;
        const int n0 = (xcd * 4 + (idx & 3)) * 64;
        const int c0 = (idx >> 2) * 64;

        const long arow = (long)xs[n0 + sr] * DDIM;
        const long brow = (long)(c0 + sr) * DDIM;

        float acc[4][4] = {};
        float4 av = *(const float4*)(emb + arow + sk);
        float4 bv = *(const float4*)(Wx  + brow + sk);

        for (int k0 = 0; k0 < DDIM; k0 += 16) {
            __syncthreads();
            As[sk+0][sr] = av.x; As[sk+1][sr] = av.y; As[sk+2][sr] = av.z; As[sk+3][sr] = av.w;
            Bs[0][sk+0][sr] = bv.x; Bs[0][sk+1][sr] = bv.y; Bs[0][sk+2][sr] = bv.z; Bs[0][sk+3][sr] = bv.w;
            __syncthreads();

            const int kn = k0 + 16;
            av = make_float4(0.f,0.f,0.f,0.f); bv = av;
            if (kn + sk < DDIM) {
                av = *(const float4*)(emb + arow + kn + sk);
                bv = *(const float4*)(Wx  + brow + kn + sk);
            }

            #pragma unroll
            for (int k = 0; k < 16; k++) {
                float4 a = *(const float4*)&As[k][trow];
                float4 b = *(const float4*)&Bs[0][k][tcol];
                float aa[4] = {a.x, a.y, a.z, a.w};
                float bb[4] = {b.x, b.y, b.z, b.w};
                #pragma unroll
                for (int i = 0; i < 4; i++)
                    #pragma unroll
                    for (int j = 0; j < 4; j++)
                        acc[i][j] = fmaf(aa[i], bb[j], acc[i][j]);
            }
        }

        const int col = c0 + tcol;
        const float4 bxa = *(const float4*)(bx + col);
        #pragma unroll
        for (int i = 0; i < 4; i++) {
            float4 r;
            r.x = acc[i][0] + bxa.x; r.y = acc[i][1] + bxa.y;
            r.z = acc[i][2] + bxa.z; r.w = acc[i][3] + bxa.w;
            *(float4*)(gx + (long)(n0 + trow + i) * GXC + col) = r;
        }
    } else {
        // ---------------- leaf block: gates i,o,u + fused pointwise ---------
        const int l   = lid;
        const int xcd = l & 7, idx = l >> 3;
        const int n0  = LEAF_FIRST + (xcd * 12 + idx % 12) * 64;
        const int c0  = (idx / 12) * 64;              // col slice within gate

        const long arow = (long)xs[n0 + sr] * DDIM;
        const long brow0 = (long)(c0 + sr) * DDIM;          // i
        const long brow1 = (long)(512 + c0 + sr) * DDIM;    // o
        const long brow2 = (long)(768 + c0 + sr) * DDIM;    // u

        float acc[3][4][4] = {};
        float4 av = *(const float4*)(emb + arow + sk);
        float4 b0 = *(const float4*)(Wx + brow0 + sk);
        float4 b1 = *(const float4*)(Wx + brow1 + sk);
        float4 b2 = *(const float4*)(Wx + brow2 + sk);

        for (int k0 = 0; k0 < DDIM; k0 += 16) {
            __syncthreads();
            As[sk+0][sr] = av.x; As[sk+1][sr] = av.y; As[sk+2][sr] = av.z; As[sk+3][sr] = av.w;
            Bs[0][sk+0][sr] = b0.x; Bs[0][sk+1][sr] = b0.y; Bs[0][sk+2][sr] = b0.z; Bs[0][sk+3][sr] = b0.w;
            Bs[1][sk+0][sr] = b1.x; Bs[1][sk+1][sr] = b1.y; Bs[1][sk+2][sr] = b1.z; Bs[1][sk+3][sr] = b1.w;
            Bs[2][sk+0][sr] = b2.x; Bs[2][sk+1][sr] = b2.y; Bs[2][sk+2][sr] = b2.z; Bs[2][sk+3][sr] = b2.w;
            __syncthreads();

            const int kn = k0 + 16;
            av = make_float4(0.f,0.f,0.f,0.f); b0 = av; b1 = av; b2 = av;
            if (kn + sk < DDIM) {
                av = *(const float4*)(emb + arow + kn + sk);
                b0 = *(const float4*)(Wx + brow0 + kn + sk);
                b1 = *(const float4*)(Wx + brow1 + kn + sk);
                b2 = *(const float4*)(Wx + brow2 + kn + sk);
            }

            #pragma unroll
            for (int k = 0; k < 16; k++) {
                float4 a = *(const float4*)&As[k][trow];
                float aa[4] = {a.x, a.y, a.z, a.w};
                #pragma unroll
                for (int g = 0; g < 3; g++) {
                    float4 b = *(const float4*)&Bs[g][k][tcol];
                    float bb[4] = {b.x, b.y, b.z, b.w};
                    #pragma unroll
                    for (int i = 0; i < 4; i++)
                        #pragma unroll
                        for (int j = 0; j < 4; j++)
                            acc[g][i][j] = fmaf(aa[i], bb[j], acc[g][i][j]);
                }
            }
        }

        const int colg = c0 + tcol;
        const float4 bxi = *(const float4*)(bx + colg);
        const float4 bxo = *(const float4*)(bx + 512 + colg);
        const float4 bxu = *(const float4*)(bx + 768 + colg);
        const float4 bhi = *(const float4*)(bh + colg);
        const float4 bho = *(const float4*)(bh + 512 + colg);
        const float4 bhu = *(const float4*)(bh + 768 + colg);
        const float bxiv[4] = {bxi.x,bxi.y,bxi.z,bxi.w};
        const float bxov[4] = {bxo.x,bxo.y,bxo.z,bxo.w};
        const float bxuv[4] = {bxu.x,bxu.y,bxu.z,bxu.w};
        const float bhiv[4] = {bhi.x,bhi.y,bhi.z,bhi.w};
        const float bhov[4] = {bho.x,bho.y,bho.z,bho.w};
        const float bhuv[4] = {bhu.x,bhu.y,bhu.z,bhu.w};
        #pragma unroll
        for (int i = 0; i < 4; i++) {
            const long row = (long)(n0 + trow + i) * HDIM + colg;
            float hh[4], cc[4];
            #pragma unroll
            for (int j = 0; j < 4; j++) {
                const float gi = (acc[0][i][j] + bxiv[j]) + bhiv[j];
                const float go = (acc[1][i][j] + bxov[j]) + bhov[j];
                const float gu = (acc[2][i][j] + bxuv[j]) + bhuv[j];
                const float c  = sigf(gi) * tanhf(gu);
                const float h  = sigf(go) * tanhf(c);
                cc[j] = c; hh[j] = h;
            }
            float4 hv, cv;
            hv.x = hh[0]; hv.y = hh[1]; hv.z = hh[2]; hv.w = hh[3];
            cv.x = cc[0]; cv.y = cc[1]; cv.z = cc[2]; cv.w = cc[3];
            *(float4*)(Hb + row) = hv;
            *(float4*)(Cb + row) = cv;
        }
    }
}

// ---------- Kernel 2: level GEMM (64x64, pipelined; round-5-proven) ---------
__global__ __launch_bounds__(256) void level_gemm(
    int first, int M, const float* __restrict__ Hb,
    const int* __restrict__ child_idx, const float* __restrict__ child_mask,
    const float* __restrict__ Wh, float* __restrict__ D)
{
    __shared__ __align__(16) float Xs[16][68];
    __shared__ __align__(16) float Ws[16][68];
    const int tid  = threadIdx.x;
    const int sec  = blockIdx.y;
    const int c0   = blockIdx.x * 64;
    const int r0   = blockIdx.z * 64;
    const int sr   = tid >> 2;
    const int sk   = (tid & 3) << 2;
    const int trow = (tid >> 4) << 2;
    const int tcol = (tid & 15) << 2;

    const float* Wg;
    if      (sec == 0) Wg = Wh;                  // i
    else if (sec == 1) Wg = Wh + 2 * WH_STRIDE;  // o
    else if (sec == 2) Wg = Wh + 3 * WH_STRIDE;  // u
    else               Wg = Wh + 1 * WH_STRIDE;  // f

    const int  nl    = c0 + sr;
    const bool valid = nl < M;
    int   ci[4];
    float cm[4] = {0.f, 0.f, 0.f, 0.f};
    if (valid) {
        const int n = first + nl;
        if (sec < 3) {
            #pragma unroll
            for (int k = 0; k < 4; k++) {
                ci[k] = child_idx[n * 4 + k];
                cm[k] = child_mask[n * 4 + k];
            }
        } else {
            ci[0] = child_idx[n * 4 + (sec - 3)];
            cm[0] = child_mask[n * 4 + (sec - 3)];
        }
    }
    const long wrow = (long)(r0 + sr) * HDIM;

    float acc[4][4] = {};
    float4 hvr[4], wvr;

    #pragma unroll
    for (int k = 0; k < 4; k++) hvr[k] = make_float4(0.f, 0.f, 0.f, 0.f);
    if (valid) {
        if (sec < 3) {
            #pragma unroll
            for (int k = 0; k < 4; k++)
                if (cm[k] != 0.f)
                    hvr[k] = *(const float4*)(Hb + ci[k] * HDIM + sk);
        } else if (cm[0] != 0.f) {
            hvr[0] = *(const float4*)(Hb + ci[0] * HDIM + sk);
        }
    }
    wvr = *(const float4*)(Wg + wrow + sk);

    for (int k0 = 0; k0 < HDIM; k0 += 16) {
        __syncthreads();
        float4 xv;
        xv.x = hvr[0].x + hvr[1].x + hvr[2].x + hvr[3].x;
        xv.y = hvr[0].y + hvr[1].y + hvr[2].y + hvr[3].y;
        xv.z = hvr[0].z + hvr[1].z + hvr[2].z + hvr[3].z;
        xv.w = hvr[0].w + hvr[1].w + hvr[2].w + hvr[3].w;
        Xs[sk+0][sr] = xv.x; Xs[sk+1][sr] = xv.y; Xs[sk+2][sr] = xv.z; Xs[sk+3][sr] = xv.w;
        Ws[sk+0][sr] = wvr.x; Ws[sk+1][sr] = wvr.y; Ws[sk+2][sr] = wvr.z; Ws[sk+3][sr] = wvr.w;
        __syncthreads();

        const int kn = k0 + 16;
        if (kn < HDIM) {
            #pragma unroll
            for (int k = 0; k < 4; k++) hvr[k] = make_float4(0.f, 0.f, 0.f, 0.f);
            if (valid) {
                if (sec < 3) {
                    #pragma unroll
                    for (int k = 0; k < 4; k++)
                        if (cm[k] != 0.f)
                            hvr[k] = *(const float4*)(Hb + ci[k] * HDIM + kn + sk);
                } else if (cm[0] != 0.f) {
                    hvr[0] = *(const float4*)(Hb + ci[0] * HDIM + kn + sk);
                }
            }
            wvr = *(const float4*)(Wg + wrow + kn + sk);
        }

        #pragma unroll
        for (int k = 0; k < 16; k++) {
            float4 a = *(const float4*)&Ws[k][trow];
            float4 b = *(const float4*)&Xs[k][tcol];
            float avv[4] = {a.x, a.y, a.z, a.w};
            float bvv[4] = {b.x, b.y, b.z, b.w};
            #pragma unroll
            for (int i = 0; i < 4; i++)
                #pragma unroll
                for (int j = 0; j < 4; j++)
                    acc[i][j] = fmaf(avv[i], bvv[j], acc[i][j]);
        }
    }

    #pragma unroll
    for (int j = 0; j < 4; j++) {
        const int col = c0 + tcol + j;
        if (col < M) {
            float4 r;
            r.x = acc[0][j]; r.y = acc[1][j]; r.z = acc[2][j]; r.w = acc[3][j];
            *(float4*)(D + ((long)(sec * M + col)) * HDIM + r0 + trow) = r;
        }
    }
}

// ---------- Kernel 3: level pointwise ---------------------------------------
__global__ __launch_bounds__(256) void level_pointwise(
    int first, int M,
    const float* __restrict__ gx, const float* __restrict__ D,
    const int* __restrict__ child_idx, const float* __restrict__ child_mask,
    const float* __restrict__ bh, float* __restrict__ Hb, float* __restrict__ Cb)
{
    const int nl = blockIdx.x;
    const int n  = first + nl;
    const int t  = threadIdx.x;
    const float di  = D[((long)(0 * M + nl)) * HDIM + t];
    const float dO  = D[((long)(1 * M + nl)) * HDIM + t];
    const float du  = D[((long)(2 * M + nl)) * HDIM + t];
    const float* g = gx + (long)n * GXC;
    const float gi  = g[t]       + bh[t]       + di;
    const float gfb = g[256 + t] + bh[256 + t];
    const float go  = g[512 + t] + bh[512 + t] + dO;
    const float gu  = g[768 + t] + bh[768 + t] + du;

    float c = sigf(gi) * tanhf(gu);
    #pragma unroll
    for (int k = 0; k < 4; k++) {
        const float m = child_mask[n * 4 + k];
        if (m != 0.f) {
            const float df = D[((long)((3 + k) * M + nl)) * HDIM + t];
            const float cc = Cb[(long)child_idx[n * 4 + k] * HDIM + t];
            c = fmaf(sigf(gfb + df), cc, c);
        }
    }
    const float h = sigf(go) * tanhf(c);
    Hb[(long)n * HDIM + t] = h;
    Cb[(long)n * HDIM + t] = c;
}

// ---------- Kernel 4: tail-fused level (M=64/16/4 ONLY; round-8-proven) -----
__global__ __launch_bounds__(256) void tail_fused(
    int first, int M,
    const float* __restrict__ gx, const int* __restrict__ child_idx,
    const float* __restrict__ child_mask, const float* __restrict__ Wh,
    const float* __restrict__ bh, float* __restrict__ Hb, float* __restrict__ Cb)
{
    __shared__ __align__(16) float Xc[4][272];
    __shared__ __align__(16) float Xh[272];
    __shared__ float Ds[7][64];

    const int t  = threadIdx.x;
    const int nl = blockIdx.x;
    const int rb = blockIdx.y;
    const int n  = first + nl;

    {
        const int ch = t >> 6;
        const int e4 = (t & 63) << 2;
        const int cidx = child_idx[n * 4 + ch];
        const float m  = child_mask[n * 4 + ch];
        float4 v = make_float4(0.f, 0.f, 0.f, 0.f);
        if (m != 0.f) v = *(const float4*)(Hb + (long)cidx * HDIM + e4);
        *(float4*)&Xc[ch][XI(e4)] = v;
    }
    __syncthreads();
    Xh[XI(t)] = Xc[0][XI(t)] + Xc[1][XI(t)] + Xc[2][XI(t)] + Xc[3][XI(t)];
    __syncthreads();

    const int q = t >> 2, j = t & 3;
    const int row = rb * 64 + q;
    const float* Wi = Wh + 0 * WH_STRIDE + (long)row * HDIM;   // gate order i,f,o,u
    const float* Wf = Wh + 1 * WH_STRIDE + (long)row * HDIM;
    const float* Wo = Wh + 2 * WH_STRIDE + (long)row * HDIM;
    const float* Wu = Wh + 3 * WH_STRIDE + (long)row * HDIM;

    float a[7] = {};
    #pragma unroll 4
    for (int kk = j * 64; kk < j * 64 + 64; kk += 4) {
        const float4 wi = *(const float4*)(Wi + kk);
        const float4 wo = *(const float4*)(Wo + kk);
        const float4 wu = *(const float4*)(Wu + kk);
        const float4 wf = *(const float4*)(Wf + kk);
        const float4 hs = *(const float4*)&Xh[XI(kk)];
        a[0] += wi.x*hs.x + wi.y*hs.y + wi.z*hs.z + wi.w*hs.w;
        a[1] += wo.x*hs.x + wo.y*hs.y + wo.z*hs.z + wo.w*hs.w;
        a[2] += wu.x*hs.x + wu.y*hs.y + wu.z*hs.z + wu.w*hs.w;
        #pragma unroll
        for (int ch = 0; ch < 4; ch++) {
            const float4 cv = *(const float4*)&Xc[ch][XI(kk)];
            a[3 + ch] += wf.x*cv.x + wf.y*cv.y + wf.z*cv.z + wf.w*cv.w;
        }
    }
    #pragma unroll
    for (int s = 0; s < 7; s++) {
        float v = a[s];
        v += __shfl_xor(v, 1, 64);
        v += __shfl_xor(v, 2, 64);
        if (j == 0) Ds[s][q] = v;
    }
    __syncthreads();

    if (t < 64) {
        const int r = rb * 64 + t;
        const float* g = gx + (long)n * GXC;
        const float gi  = g[r]       + bh[r]       + Ds[0][t];
        const float gfb = g[256 + r] + bh[256 + r];
        const float go  = g[512 + r] + bh[512 + r] + Ds[1][t];
        const float gu  = g[768 + r] + bh[768 + r] + Ds[2][t];
        float c = sigf(gi) * tanhf(gu);
        #pragma unroll
        for (int ch = 0; ch < 4; ch++) {
            const float m = child_mask[n * 4 + ch];
            if (m != 0.f) {
                const float cc = Cb[(long)child_idx[n * 4 + ch] * HDIM + r];
                c = fmaf(sigf(gfb + Ds[3 + ch][t]), cc, c);
            }
        }
        const float h = sigf(go) * tanhf(c);
        Hb[(long)n * HDIM + r] = h;
        Cb[(long)n * HDIM + r] = c;
    }
}

// ---------- Kernel 5: root — single block, GEMV + pointwise + out -----------
// Thread t owns output row t: 4 W-row reads (4KB) from L2, 7 dots over LDS X.
// Round-9-proven (absmax 0.0).
__global__ __launch_bounds__(256) void root_kernel(
    const float* __restrict__ gx, const int* __restrict__ child_idx,
    const float* __restrict__ child_mask, const float* __restrict__ Wh,
    const float* __restrict__ bh, float* __restrict__ Hb, float* __restrict__ Cb,
    const float* __restrict__ Wout, const float* __restrict__ bout,
    float* __restrict__ out)
{
    __shared__ __align__(16) float Xc[4][272];
    __shared__ __align__(16) float Xh[272];
    __shared__ float hroot[HDIM];
    __shared__ float logits[4];

    const int t = threadIdx.x;

    {
        const int ch = t >> 6;
        const int e4 = (t & 63) << 2;
        const int cidx = child_idx[ch];          // node 0's children
        const float m  = child_mask[ch];
        float4 v = make_float4(0.f, 0.f, 0.f, 0.f);
        if (m != 0.f) v = *(const float4*)(Hb + (long)cidx * HDIM + e4);
        *(float4*)&Xc[ch][XI(e4)] = v;
    }
    __syncthreads();
    Xh[XI(t)] = Xc[0][XI(t)] + Xc[1][XI(t)] + Xc[2][XI(t)] + Xc[3][XI(t)];
    __syncthreads();

    // GEMV: thread t = row t of all 4 gate matrices.
    const float* Wi = Wh + 0 * WH_STRIDE + (long)t * HDIM;
    const float* Wf = Wh + 1 * WH_STRIDE + (long)t * HDIM;
    const float* Wo = Wh + 2 * WH_STRIDE + (long)t * HDIM;
    const float* Wu = Wh + 3 * WH_STRIDE + (long)t * HDIM;
    float a[7] = {};
    #pragma unroll 4
    for (int kk = 0; kk < HDIM; kk += 4) {
        const float4 wi = *(const float4*)(Wi + kk);
        const float4 wo = *(const float4*)(Wo + kk);
        const float4 wu = *(const float4*)(Wu + kk);
        const float4 wf = *(const float4*)(Wf + kk);
        const float4 hs = *(const float4*)&Xh[XI(kk)];
        a[0] += wi.x*hs.x + wi.y*hs.y + wi.z*hs.z + wi.w*hs.w;
        a[1] += wo.x*hs.x + wo.y*hs.y + wo.z*hs.z + wo.w*hs.w;
        a[2] += wu.x*hs.x + wu.y*hs.y + wu.z*hs.z + wu.w*hs.w;
        #pragma unroll
        for (int ch = 0; ch < 4; ch++) {
            const float4 cv = *(const float4*)&Xc[ch][XI(kk)];
            a[3 + ch] += wf.x*cv.x + wf.y*cv.y + wf.z*cv.z + wf.w*cv.w;
        }
    }

    // pointwise row t of node 0
    {
        const float* g = gx;   // row 0
        const float gi  = g[t]       + bh[t]       + a[0];
        const float gfb = g[256 + t] + bh[256 + t];
        const float go  = g[512 + t] + bh[512 + t] + a[1];
        const float gu  = g[768 + t] + bh[768 + t] + a[2];
        float c = sigf(gi) * tanhf(gu);
        #pragma unroll
        for (int ch = 0; ch < 4; ch++) {
            const float m = child_mask[ch];
            if (m != 0.f) {
                const float cc = Cb[(long)child_idx[ch] * HDIM + t];
                c = fmaf(sigf(gfb + a[3 + ch]), cc, c);
            }
        }
        const float h = sigf(go) * tanhf(c);
        Hb[t] = h;
        Cb[t] = c;
        hroot[t] = h;
    }
    __syncthreads();

    // logits + log_softmax
    {
        const int o    = t >> 6;
        const int lane = t & 63;
        float s = 0.f;
        for (int jj = lane; jj < HDIM; jj += 64)
            s = fmaf(Wout[o * HDIM + jj], hroot[jj], s);
        #pragma unroll
        for (int off = 32; off > 0; off >>= 1)
            s += __shfl_down(s, off, 64);
        if (lane == 0) logits[o] = s + bout[o];
        __syncthreads();
        if (t == 0) {
            float m = logits[0];
            #pragma unroll
            for (int i = 1; i < 4; i++) m = fmaxf(m, logits[i]);
            float se = 0.f;
            #pragma unroll
            for (int i = 0; i < 4; i++) se += __expf(logits[i] - m);
            const float lse = m + __logf(se);
            #pragma unroll
            for (int i = 0; i < 4; i++) out[i] = logits[i] - lse;
        }
    }
}

extern "C" void kernel_launch(void* const* d_in, const int* in_sizes, int n_in,
                              void* d_out, int out_size, void* d_ws, size_t ws_size,
                              hipStream_t stream)
{
    const int*   xs         = (const int*)  d_in[0];
    const int*   child_idx  = (const int*)  d_in[1];
    const float* child_mask = (const float*)d_in[2];
    const float* emb        = (const float*)d_in[3];
    const float* Wx         = (const float*)d_in[4];
    const float* bx         = (const float*)d_in[5];
    const float* Wh         = (const float*)d_in[6];
    const float* bh         = (const float*)d_in[7];
    const float* Wout       = (const float*)d_in[8];
    const float* bout       = (const float*)d_in[9];
    float* out = (float*)d_out;

    float* gxb = (float*)d_ws;
    float* Hb  = gxb + (size_t)N_NODES * GXC;
    float* Cb  = Hb  + (size_t)N_NODES * HDIM;
    // D aliases gx leaf rows (never written by gx_leaf_gemm): rows 2048.. free.
    float* Dbuf = gxb + (size_t)LEAF_FIRST * GXC;

    gx_leaf_gemm<<<896, 256, 0, stream>>>(xs, emb, Wx, bx, bh, gxb, Hb, Cb);

    // Levels M=683,1024,256: proven pipelined pair.
    const int pfb[3] = {1365, 341, 85};
    const int pcb[3] = { 683, 1024, 256};
    for (int p = 0; p < 3; p++) {
        const int M = pcb[p];
        dim3 grid((M + 63) / 64, 7, 4);
        level_gemm<<<grid, 256, 0, stream>>>(pfb[p], M, Hb, child_idx, child_mask,
                                             Wh, Dbuf);
        level_pointwise<<<M, 256, 0, stream>>>(pfb[p], M, gxb, Dbuf, child_idx,
                                               child_mask, bh, Hb, Cb);
    }

    // Levels M=64,16,4: single fused dispatch each.
    const int pft[3] = {21, 5, 1};
    const int pct[3] = {64, 16, 4};
    for (int p = 0; p < 3; p++) {
        dim3 grid(pct[p], 4);
        tail_fused<<<grid, 256, 0, stream>>>(pft[p], pct[p], gxb, child_idx,
                                             child_mask, Wh, bh, Hb, Cb);
    }

    // Root: single block (GEMV + pointwise + out).
    root_kernel<<<1, 256, 0, stream>>>(gxb, child_idx, child_mask, Wh, bh,
                                       Hb, Cb, Wout, bout, out);
}

// Round 15
// 290.760 us; speedup vs baseline: 1.0470x; 1.0470x over previous
//
#include <hip/hip_runtime.h>

// ChildSumTreeLSTM on a static 4-ary heap tree.
// N=8192, H=256, D=300, K=4, OUT=4. Leaves = 2048..8191. Internal 0..2047 in 7 levels.
// Workspace: gx [8192][1024] f32, Hb [8192][256] f32, Cb [8192][256] f32.
// D (big-level scratch, <=7.3MB) aliases gx rows 2048.. (leaf gx never written).
//
// FINAL structure (12 dispatches) — round-13 champion (292.6us, absmax 0.0):
//   1. gx_leaf_gemm — LPT order (384 fat leaf blocks FIRST: 3 gates +
//        in-register leaf pointwise -> Hb/Cb; then 512 internal 64x64 gx
//        tiles), XCD-grouped for emb L2 locality.          [67.3us]
//   2-7. levels M=683,1024,256: level_gemm (64x64, pipelined) +
//        level_pointwise (proven pair).
//   8-10. levels M=64,16,4: tail_fused (W 256KB/block from L2, 2 syncs).
//   11-12. root: level_gemm + level_pointwise(do_out).
// Measured decision space (rounds 1-14):
//   - grid barriers / device fences: +170-200us each (r1,r7) — never.
//   - fused GEMV levels: only M<=64 (r8); lose at M>=256 (r3,r9,r12).
//   - chunked W-LDS fused levels: lose at all grid sizes (r4,r6).
//   - gx: 64x64/many-blocks wins (r5,r9,r10); leaf-fusion+LPT = 67.3 (r12).
//   - root: pair beats single-block (r14: serial 1MB W stream > saved gap).
//   - remaining ~155us = 11 dispatch boundaries (~14us each), not
//     addressable from kernel source under the no-cross-block-sync rule.

#define N_NODES 8192
#define HDIM 256
#define DDIM 300
#define GXC 1024
#define LEAF_FIRST 2048
#define WH_STRIDE 65536   // 256*256
#define XI(k) ((k) + (((k) >> 6) << 2))   // padded X index (bank spread)

__device__ __forceinline__ float sigf(float x) { return 1.0f / (1.0f + __expf(-x)); }

// ---------- Kernel 1: gx internal rows + fused leaf h/c (LPT order) ---------
// lid 0..383   leaf:     xcd=l&7, idx=l>>3: rowt=xcd*12+idx%12 (0..95),
//                        slice=idx/12 (0..3). 64 rows x 64-col slice of
//                        gates {i,o,u} + in-register leaf pointwise -> Hb/Cb.
// lid 384..895 internal: l=lid-384: xcd=l&7, idx=l>>3: rowt=xcd*4+(idx&3),
//                        colt=idx>>2. Round-5-proven 64x64 gx tile.
__global__ __launch_bounds__(256) void gx_leaf_gemm(
    const int* __restrict__ xs, const float* __restrict__ emb,
    const float* __restrict__ Wx, const float* __restrict__ bx,
    const float* __restrict__ bh, float* __restrict__ gx,
    float* __restrict__ Hb, float* __restrict__ Cb)
{
    __shared__ __align__(16) float As[16][68];
    __shared__ __align__(16) float Bs[3][16][68];
    const int lid  = blockIdx.x;
    const int tid  = threadIdx.x;
    const int sr   = tid >> 2;
    const int sk   = (tid & 3) << 2;
    const int trow = (tid >> 4) << 2;
    const int tcol = (tid & 15) << 2;

    if (lid >= 384) {
        // ---------------- internal 64x64 tile (round-5-proven) --------------
        const int l = lid - 384;
        const int xcd = l & 7, idx = l >> 3;
        const int n0 = (xcd * 4 + (idx & 3)) * 64;
        const int c0 = (idx >> 2) * 64;

        const long arow = (long)xs[n0 + sr] * DDIM;
        const long brow = (long)(c0 + sr) * DDIM;

        float acc[4][4] = {};
        float4 av = *(const float4*)(emb + arow + sk);
        float4 bv = *(const float4*)(Wx  + brow + sk);

        for (int k0 = 0; k0 < DDIM; k0 += 16) {
            __syncthreads();
            As[sk+0][sr] = av.x; As[sk+1][sr] = av.y; As[sk+2][sr] = av.z; As[sk+3][sr] = av.w;
            Bs[0][sk+0][sr] = bv.x; Bs[0][sk+1][sr] = bv.y; Bs[0][sk+2][sr] = bv.z; Bs[0][sk+3][sr] = bv.w;
            __syncthreads();

            const int kn = k0 + 16;
            av = make_float4(0.f,0.f,0.f,0.f); bv = av;
            if (kn + sk < DDIM) {
                av = *(const float4*)(emb + arow + kn + sk);
                bv = *(const float4*)(Wx  + brow + kn + sk);
            }

            #pragma unroll
            for (int k = 0; k < 16; k++) {
                float4 a = *(const float4*)&As[k][trow];
                float4 b = *(const float4*)&Bs[0][k][tcol];
                float aa[4] = {a.x, a.y, a.z, a.w};
                float bb[4] = {b.x, b.y, b.z, b.w};
                #pragma unroll
                for (int i = 0; i < 4; i++)
                    #pragma unroll
                    for (int j = 0; j < 4; j++)
                        acc[i][j] = fmaf(aa[i], bb[j], acc[i][j]);
            }
        }

        const int col = c0 + tcol;
        const float4 bxa = *(const float4*)(bx + col);
        #pragma unroll
        for (int i = 0; i < 4; i++) {
            float4 r;
            r.x = acc[i][0] + bxa.x; r.y = acc[i][1] + bxa.y;
            r.z = acc[i][2] + bxa.z; r.w = acc[i][3] + bxa.w;
            *(float4*)(gx + (long)(n0 + trow + i) * GXC + col) = r;
        }
    } else {
        // ---------------- leaf block: gates i,o,u + fused pointwise ---------
        const int l   = lid;
        const int xcd = l & 7, idx = l >> 3;
        const int n0  = LEAF_FIRST + (xcd * 12 + idx % 12) * 64;
        const int c0  = (idx / 12) * 64;              // col slice within gate

        const long arow = (long)xs[n0 + sr] * DDIM;
        const long brow0 = (long)(c0 + sr) * DDIM;          // i
        const long brow1 = (long)(512 + c0 + sr) * DDIM;    // o
        const long brow2 = (long)(768 + c0 + sr) * DDIM;    // u

        float acc[3][4][4] = {};
        float4 av = *(const float4*)(emb + arow + sk);
        float4 b0 = *(const float4*)(Wx + brow0 + sk);
        float4 b1 = *(const float4*)(Wx + brow1 + sk);
        float4 b2 = *(const float4*)(Wx + brow2 + sk);

        for (int k0 = 0; k0 < DDIM; k0 += 16) {
            __syncthreads();
            As[sk+0][sr] = av.x; As[sk+1][sr] = av.y; As[sk+2][sr] = av.z; As[sk+3][sr] = av.w;
            Bs[0][sk+0][sr] = b0.x; Bs[0][sk+1][sr] = b0.y; Bs[0][sk+2][sr] = b0.z; Bs[0][sk+3][sr] = b0.w;
            Bs[1][sk+0][sr] = b1.x; Bs[1][sk+1][sr] = b1.y; Bs[1][sk+2][sr] = b1.z; Bs[1][sk+3][sr] = b1.w;
            Bs[2][sk+0][sr] = b2.x; Bs[2][sk+1][sr] = b2.y; Bs[2][sk+2][sr] = b2.z; Bs[2][sk+3][sr] = b2.w;
            __syncthreads();

            const int kn = k0 + 16;
            av = make_float4(0.f,0.f,0.f,0.f); b0 = av; b1 = av; b2 = av;
            if (kn + sk < DDIM) {
                av = *(const float4*)(emb + arow + kn + sk);
                b0 = *(const float4*)(Wx + brow0 + kn + sk);
                b1 = *(const float4*)(Wx + brow1 + kn + sk);
                b2 = *(const float4*)(Wx + brow2 + kn + sk);
            }

            #pragma unroll
            for (int k = 0; k < 16; k++) {
                float4 a = *(const float4*)&As[k][trow];
                float aa[4] = {a.x, a.y, a.z, a.w};
                #pragma unroll
                for (int g = 0; g < 3; g++) {
                    float4 b = *(const float4*)&Bs[g][k][tcol];
                    float bb[4] = {b.x, b.y, b.z, b.w};
                    #pragma unroll
                    for (int i = 0; i < 4; i++)
                        #pragma unroll
                        for (int j = 0; j < 4; j++)
                            acc[g][i][j] = fmaf(aa[i], bb[j], acc[g][i][j]);
                }
            }
        }

        const int colg = c0 + tcol;
        const float4 bxi = *(const float4*)(bx + colg);
        const float4 bxo = *(const float4*)(bx + 512 + colg);
        const float4 bxu = *(const float4*)(bx + 768 + colg);
        const float4 bhi = *(const float4*)(bh + colg);
        const float4 bho = *(const float4*)(bh + 512 + colg);
        const float4 bhu = *(const float4*)(bh + 768 + colg);
        const float bxiv[4] = {bxi.x,bxi.y,bxi.z,bxi.w};
        const float bxov[4] = {bxo.x,bxo.y,bxo.z,bxo.w};
        const float bxuv[4] = {bxu.x,bxu.y,bxu.z,bxu.w};
        const float bhiv[4] = {bhi.x,bhi.y,bhi.z,bhi.w};
        const float bhov[4] = {bho.x,bho.y,bho.z,bho.w};
        const float bhuv[4] = {bhu.x,bhu.y,bhu.z,bhu.w};
        #pragma unroll
        for (int i = 0; i < 4; i++) {
            const long row = (long)(n0 + trow + i) * HDIM + colg;
            float hh[4], cc[4];
            #pragma unroll
            for (int j = 0; j < 4; j++) {
                const float gi = (acc[0][i][j] + bxiv[j]) + bhiv[j];
                const float go = (acc[1][i][j] + bxov[j]) + bhov[j];
                const float gu = (acc[2][i][j] + bxuv[j]) + bhuv[j];
                const float c  = sigf(gi) * tanhf(gu);
                const float h  = sigf(go) * tanhf(c);
                cc[j] = c; hh[j] = h;
            }
            float4 hv, cv;
            hv.x = hh[0]; hv.y = hh[1]; hv.z = hh[2]; hv.w = hh[3];
            cv.x = cc[0]; cv.y = cc[1]; cv.z = cc[2]; cv.w = cc[3];
            *(float4*)(Hb + row) = hv;
            *(float4*)(Cb + row) = cv;
        }
    }
}

// ---------- Kernel 2: level GEMM (64x64, pipelined; round-5-proven) ---------
__global__ __launch_bounds__(256) void level_gemm(
    int first, int M, const float* __restrict__ Hb,
    const int* __restrict__ child_idx, const float* __restrict__ child_mask,
    const float* __restrict__ Wh, float* __restrict__ D)
{
    __shared__ __align__(16) float Xs[16][68];
    __shared__ __align__(16) float Ws[16][68];
    const int tid  = threadIdx.x;
    const int sec  = blockIdx.y;
    const int c0   = blockIdx.x * 64;
    const int r0   = blockIdx.z * 64;
    const int sr   = tid >> 2;
    const int sk   = (tid & 3) << 2;
    const int trow = (tid >> 4) << 2;
    const int tcol = (tid & 15) << 2;

    const float* Wg;
    if      (sec == 0) Wg = Wh;                  // i
    else if (sec == 1) Wg = Wh + 2 * WH_STRIDE;  // o
    else if (sec == 2) Wg = Wh + 3 * WH_STRIDE;  // u
    else               Wg = Wh + 1 * WH_STRIDE;  // f

    const int  nl    = c0 + sr;
    const bool valid = nl < M;
    int   ci[4];
    float cm[4] = {0.f, 0.f, 0.f, 0.f};
    if (valid) {
        const int n = first + nl;
        if (sec < 3) {
            #pragma unroll
            for (int k = 0; k < 4; k++) {
                ci[k] = child_idx[n * 4 + k];
                cm[k] = child_mask[n * 4 + k];
            }
        } else {
            ci[0] = child_idx[n * 4 + (sec - 3)];
            cm[0] = child_mask[n * 4 + (sec - 3)];
        }
    }
    const long wrow = (long)(r0 + sr) * HDIM;

    float acc[4][4] = {};
    float4 hvr[4], wvr;

    #pragma unroll
    for (int k = 0; k < 4; k++) hvr[k] = make_float4(0.f, 0.f, 0.f, 0.f);
    if (valid) {
        if (sec < 3) {
            #pragma unroll
            for (int k = 0; k < 4; k++)
                if (cm[k] != 0.f)
                    hvr[k] = *(const float4*)(Hb + ci[k] * HDIM + sk);
        } else if (cm[0] != 0.f) {
            hvr[0] = *(const float4*)(Hb + ci[0] * HDIM + sk);
        }
    }
    wvr = *(const float4*)(Wg + wrow + sk);

    for (int k0 = 0; k0 < HDIM; k0 += 16) {
        __syncthreads();
        float4 xv;
        xv.x = hvr[0].x + hvr[1].x + hvr[2].x + hvr[3].x;
        xv.y = hvr[0].y + hvr[1].y + hvr[2].y + hvr[3].y;
        xv.z = hvr[0].z + hvr[1].z + hvr[2].z + hvr[3].z;
        xv.w = hvr[0].w + hvr[1].w + hvr[2].w + hvr[3].w;
        Xs[sk+0][sr] = xv.x; Xs[sk+1][sr] = xv.y; Xs[sk+2][sr] = xv.z; Xs[sk+3][sr] = xv.w;
        Ws[sk+0][sr] = wvr.x; Ws[sk+1][sr] = wvr.y; Ws[sk+2][sr] = wvr.z; Ws[sk+3][sr] = wvr.w;
        __syncthreads();

        const int kn = k0 + 16;
        if (kn < HDIM) {
            #pragma unroll
            for (int k = 0; k < 4; k++) hvr[k] = make_float4(0.f, 0.f, 0.f, 0.f);
            if (valid) {
                if (sec < 3) {
                    #pragma unroll
                    for (int k = 0; k < 4; k++)
                        if (cm[k] != 0.f)
                            hvr[k] = *(const float4*)(Hb + ci[k] * HDIM + kn + sk);
                } else if (cm[0] != 0.f) {
                    hvr[0] = *(const float4*)(Hb + ci[0] * HDIM + kn + sk);
                }
            }
            wvr = *(const float4*)(Wg + wrow + kn + sk);
        }

        #pragma unroll
        for (int k = 0; k < 16; k++) {
            float4 a = *(const float4*)&Ws[k][trow];
            float4 b = *(const float4*)&Xs[k][tcol];
            float avv[4] = {a.x, a.y, a.z, a.w};
            float bvv[4] = {b.x, b.y, b.z, b.w};
            #pragma unroll
            for (int i = 0; i < 4; i++)
                #pragma unroll
                for (int j = 0; j < 4; j++)
                    acc[i][j] = fmaf(avv[i], bvv[j], acc[i][j]);
        }
    }

    #pragma unroll
    for (int j = 0; j < 4; j++) {
        const int col = c0 + tcol + j;
        if (col < M) {
            float4 r;
            r.x = acc[0][j]; r.y = acc[1][j]; r.z = acc[2][j]; r.w = acc[3][j];
            *(float4*)(D + ((long)(sec * M + col)) * HDIM + r0 + trow) = r;
        }
    }
}

// ---------- Kernel 3: level pointwise (do_out folds logits on root) ---------
__global__ __launch_bounds__(256) void level_pointwise(
    int first, int M, int do_out,
    const float* __restrict__ gx, const float* __restrict__ D,
    const int* __restrict__ child_idx, const float* __restrict__ child_mask,
    const float* __restrict__ bh, float* __restrict__ Hb, float* __restrict__ Cb,
    const float* __restrict__ Wout, const float* __restrict__ bout,
    float* __restrict__ out)
{
    __shared__ float hroot[HDIM];
    __shared__ float logits[4];
    const int nl = blockIdx.x;
    const int n  = first + nl;
    const int t  = threadIdx.x;
    const float di  = D[((long)(0 * M + nl)) * HDIM + t];
    const float dO  = D[((long)(1 * M + nl)) * HDIM + t];
    const float du  = D[((long)(2 * M + nl)) * HDIM + t];
    const float* g = gx + (long)n * GXC;
    const float gi  = g[t]       + bh[t]       + di;
    const float gfb = g[256 + t] + bh[256 + t];
    const float go  = g[512 + t] + bh[512 + t] + dO;
    const float gu  = g[768 + t] + bh[768 + t] + du;

    float c = sigf(gi) * tanhf(gu);
    #pragma unroll
    for (int k = 0; k < 4; k++) {
        const float m = child_mask[n * 4 + k];
        if (m != 0.f) {
            const float df = D[((long)((3 + k) * M + nl)) * HDIM + t];
            const float cc = Cb[(long)child_idx[n * 4 + k] * HDIM + t];
            c = fmaf(sigf(gfb + df), cc, c);
        }
    }
    const float h = sigf(go) * tanhf(c);
    Hb[(long)n * HDIM + t] = h;
    Cb[(long)n * HDIM + t] = c;

    if (do_out) {
        hroot[t] = h;                       // n==0, single block
        __syncthreads();
        const int o    = t >> 6;
        const int lane = t & 63;
        float s = 0.f;
        for (int jj = lane; jj < HDIM; jj += 64)
            s = fmaf(Wout[o * HDIM + jj], hroot[jj], s);
        #pragma unroll
        for (int off = 32; off > 0; off >>= 1)
            s += __shfl_down(s, off, 64);
        if (lane == 0) logits[o] = s + bout[o];
        __syncthreads();
        if (t == 0) {
            float m = logits[0];
            #pragma unroll
            for (int i = 1; i < 4; i++) m = fmaxf(m, logits[i]);
            float se = 0.f;
            #pragma unroll
            for (int i = 0; i < 4; i++) se += __expf(logits[i] - m);
            const float lse = m + __logf(se);
            #pragma unroll
            for (int i = 0; i < 4; i++) out[i] = logits[i] - lse;
        }
    }
}

// ---------- Kernel 4: tail-fused level (M=64/16/4 ONLY; round-8-proven) -----
__global__ __launch_bounds__(256) void tail_fused(
    int first, int M,
    const float* __restrict__ gx, const int* __restrict__ child_idx,
    const float* __restrict__ child_mask, const float* __restrict__ Wh,
    const float* __restrict__ bh, float* __restrict__ Hb, float* __restrict__ Cb)
{
    __shared__ __align__(16) float Xc[4][272];
    __shared__ __align__(16) float Xh[272];
    __shared__ float Ds[7][64];

    const int t  = threadIdx.x;
    const int nl = blockIdx.x;
    const int rb = blockIdx.y;
    const int n  = first + nl;

    {
        const int ch = t >> 6;
        const int e4 = (t & 63) << 2;
        const int cidx = child_idx[n * 4 + ch];
        const float m  = child_mask[n * 4 + ch];
        float4 v = make_float4(0.f, 0.f, 0.f, 0.f);
        if (m != 0.f) v = *(const float4*)(Hb + (long)cidx * HDIM + e4);
        *(float4*)&Xc[ch][XI(e4)] = v;
    }
    __syncthreads();
    Xh[XI(t)] = Xc[0][XI(t)] + Xc[1][XI(t)] + Xc[2][XI(t)] + Xc[3][XI(t)];
    __syncthreads();

    const int q = t >> 2, j = t & 3;
    const int row = rb * 64 + q;
    const float* Wi = Wh + 0 * WH_STRIDE + (long)row * HDIM;   // gate order i,f,o,u
    const float* Wf = Wh + 1 * WH_STRIDE + (long)row * HDIM;
    const float* Wo = Wh + 2 * WH_STRIDE + (long)row * HDIM;
    const float* Wu = Wh + 3 * WH_STRIDE + (long)row * HDIM;

    float a[7] = {};
    #pragma unroll 4
    for (int kk = j * 64; kk < j * 64 + 64; kk += 4) {
        const float4 wi = *(const float4*)(Wi + kk);
        const float4 wo = *(const float4*)(Wo + kk);
        const float4 wu = *(const float4*)(Wu + kk);
        const float4 wf = *(const float4*)(Wf + kk);
        const float4 hs = *(const float4*)&Xh[XI(kk)];
        a[0] += wi.x*hs.x + wi.y*hs.y + wi.z*hs.z + wi.w*hs.w;
        a[1] += wo.x*hs.x + wo.y*hs.y + wo.z*hs.z + wo.w*hs.w;
        a[2] += wu.x*hs.x + wu.y*hs.y + wu.z*hs.z + wu.w*hs.w;
        #pragma unroll
        for (int ch = 0; ch < 4; ch++) {
            const float4 cv = *(const float4*)&Xc[ch][XI(kk)];
            a[3 + ch] += wf.x*cv.x + wf.y*cv.y + wf.z*cv.z + wf.w*cv.w;
        }
    }
    #pragma unroll
    for (int s = 0; s < 7; s++) {
        float v = a[s];
        v += __shfl_xor(v, 1, 64);
        v += __shfl_xor(v, 2, 64);
        if (j == 0) Ds[s][q] = v;
    }
    __syncthreads();

    if (t < 64) {
        const int r = rb * 64 + t;
        const float* g = gx + (long)n * GXC;
        const float gi  = g[r]       + bh[r]       + Ds[0][t];
        const float gfb = g[256 + r] + bh[256 + r];
        const float go  = g[512 + r] + bh[512 + r] + Ds[1][t];
        const float gu  = g[768 + r] + bh[768 + r] + Ds[2][t];
        float c = sigf(gi) * tanhf(gu);
        #pragma unroll
        for (int ch = 0; ch < 4; ch++) {
            const float m = child_mask[n * 4 + ch];
            if (m != 0.f) {
                const float cc = Cb[(long)child_idx[n * 4 + ch] * HDIM + r];
                c = fmaf(sigf(gfb + Ds[3 + ch][t]), cc, c);
            }
        }
        const float h = sigf(go) * tanhf(c);
        Hb[(long)n * HDIM + r] = h;
        Cb[(long)n * HDIM + r] = c;
    }
}

extern "C" void kernel_launch(void* const* d_in, const int* in_sizes, int n_in,
                              void* d_out, int out_size, void* d_ws, size_t ws_size,
                              hipStream_t stream)
{
    const int*   xs         = (const int*)  d_in[0];
    const int*   child_idx  = (const int*)  d_in[1];
    const float* child_mask = (const float*)d_in[2];
    const float* emb        = (const float*)d_in[3];
    const float* Wx         = (const float*)d_in[4];
    const float* bx         = (const float*)d_in[5];
    const float* Wh         = (const float*)d_in[6];
    const float* bh         = (const float*)d_in[7];
    const float* Wout       = (const float*)d_in[8];
    const float* bout       = (const float*)d_in[9];
    float* out = (float*)d_out;

    float* gxb = (float*)d_ws;
    float* Hb  = gxb + (size_t)N_NODES * GXC;
    float* Cb  = Hb  + (size_t)N_NODES * HDIM;
    // D aliases gx leaf rows (never written by gx_leaf_gemm): rows 2048.. free.
    float* Dbuf = gxb + (size_t)LEAF_FIRST * GXC;

    gx_leaf_gemm<<<896, 256, 0, stream>>>(xs, emb, Wx, bx, bh, gxb, Hb, Cb);

    // Levels M=683,1024,256: proven pipelined pair.
    const int pfb[3] = {1365, 341, 85};
    const int pcb[3] = { 683, 1024, 256};
    for (int p = 0; p < 3; p++) {
        const int M = pcb[p];
        dim3 grid((M + 63) / 64, 7, 4);
        level_gemm<<<grid, 256, 0, stream>>>(pfb[p], M, Hb, child_idx, child_mask,
                                             Wh, Dbuf);
        level_pointwise<<<M, 256, 0, stream>>>(pfb[p], M, 0, gxb, Dbuf, child_idx,
                                               child_mask, bh, Hb, Cb,
                                               Wout, bout, out);
    }

    // Levels M=64,16,4: single fused dispatch each.
    const int pft[3] = {21, 5, 1};
    const int pct[3] = {64, 16, 4};
    for (int p = 0; p < 3; p++) {
        dim3 grid(pct[p], 4);
        tail_fused<<<grid, 256, 0, stream>>>(pft[p], pct[p], gxb, child_idx,
                                             child_mask, Wh, bh, Hb, Cb);
    }

    // Root: pair (out folded into the pointwise).
    {
        dim3 grid(1, 7, 4);
        level_gemm<<<grid, 256, 0, stream>>>(0, 1, Hb, child_idx, child_mask,
                                             Wh, Dbuf);
        level_pointwise<<<1, 256, 0, stream>>>(0, 1, 1, gxb, Dbuf, child_idx,
                                               child_mask, bh, Hb, Cb,
                                               Wout, bout, out);
    }
}